// Round 11
// baseline (1521.773 us; speedup 1.0000x reference)
//
#include <hip/hip_runtime.h>
#include <hip/hip_bf16.h>

#define N_ 1024
#define M_ 1152
#define L_ 32
#define NATSTRIDE (L_*M_)   // 36864
#define CONVK 129
#define OUTW 1024
#define NSTEP 31

typedef __attribute__((ext_vector_type(8))) short short8;
typedef __attribute__((ext_vector_type(4))) float f32x4;
typedef unsigned long long u64;

__device__ __forceinline__ unsigned short f2bf(float f) {
    unsigned int u = __float_as_uint(f);
    u += 0x7FFFu + ((u >> 16) & 1u);   // round-to-nearest-even
    return (unsigned short)(u >> 16);
}
__device__ __forceinline__ float bf2f(unsigned short b) {
    return __uint_as_float(((unsigned int)b) << 16);
}

// Split convW[m][k][2] -> w0t[m][k], w1t[m][k] (bf16, k-contiguous = B^T layout)
__global__ __launch_bounds__(256) void build_wsplit(const float* __restrict__ convW,
                                                    unsigned short* __restrict__ w0t,
                                                    unsigned short* __restrict__ w1t) {
    int idx = blockIdx.x * blockDim.x + threadIdx.x;
    if (idx >= M_ * M_) return;
    int m = idx / M_;
    int k = idx - m * M_;
    const float* s = convW + (size_t)m * (2 * M_) + 2 * k;
    w0t[idx] = f2bf(s[0]);
    w1t[idx] = f2bf(s[1]);
}

// h0 = bf16(NATree[:, L-1, :])
__global__ __launch_bounds__(256) void build_h0(const float* __restrict__ nat,
                                                unsigned short* __restrict__ h0) {
    int idx = blockIdx.x * blockDim.x + threadIdx.x;
    if (idx >= N_ * M_) return;
    int n = idx / M_;
    int m = idx - n * M_;
    h0[idx] = f2bf(nat[(size_t)n * NATSTRIDE + (size_t)(L_ - 1) * M_ + m]);
}

// rbf[t][n][m] = bf16(NATree[n][30-t][m])  for t = 0..30
__global__ __launch_bounds__(256) void build_rbf(const float* __restrict__ nat,
                                                 unsigned short* __restrict__ rbf) {
    int idx = blockIdx.x * blockDim.x + threadIdx.x;   // one thread per 8 elems
    if (idx >= NSTEP * N_ * M_ / 8) return;
    int o = idx * 8;
    int t = o / (N_ * M_);
    int rem = o - t * (N_ * M_);
    int n = rem / M_;
    int m = rem - n * M_;
    int l = (NSTEP - 1) - t;
    const float* s = nat + (size_t)n * NATSTRIDE + (size_t)l * M_ + m;
    f32x4 v0 = *(const f32x4*)(s);
    f32x4 v1 = *(const f32x4*)(s + 4);
    short8 tt;
    #pragma unroll
    for (int e = 0; e < 4; ++e) {
        tt[e]     = (short)f2bf(v0[e]);
        tt[4 + e] = (short)f2bf(v1[e]);
    }
    *(short8*)(rbf + o) = tt;
}

// ---------------- Phase 1: Rpre = bf16( r_t @ W0^T + b ) for all t (R6 config) ----------------
#define P_BM 128
#define P_BN 128
#define P_BK 64
#define P_NT (M_ / P_BK)    // 18
#define P_LDP 72

__global__ __launch_bounds__(256) void rpre_gemm(
    const unsigned short* __restrict__ rbf,
    const unsigned short* __restrict__ w0t,
    const float* __restrict__ convb,
    unsigned short* __restrict__ rpre)
{
    __shared__ __align__(16) unsigned short As[2][P_BM * P_LDP];
    __shared__ __align__(16) unsigned short Bs[2][P_BN * P_LDP];

    int tid = threadIdx.x;
    int lane = tid & 63;
    int w = tid >> 6;
    int wr = w >> 1, wc = w & 1;
    int raw = blockIdx.y * 9 + blockIdx.x;
    int logical = (raw & 7) * 279 + (raw >> 3);   // 2232 = 8*279 bijective chunked swizzle
    int bx = logical % 9, by = logical / 9;
    int n0 = by * P_BM;
    int m0 = bx * P_BN;

    int lr = lane & 15;
    int lk = (lane >> 4) * 8;
    int srow = tid >> 3;
    int skcol = (tid & 7) * 8;

    f32x4 acc[4][4] = {};

    auto loadTile = [&](int it, short8 a[4], short8 b[4]) {
        int kb = it * P_BK;
        #pragma unroll
        for (int i = 0; i < 4; ++i) {
            int row = srow + i * 32;
            a[i] = *(const short8*)(rbf + (size_t)(n0 + row) * M_ + kb + skcol);
            b[i] = *(const short8*)(w0t + (size_t)(m0 + row) * M_ + kb + skcol);
        }
    };
    auto writeTile = [&](int buf, short8 a[4], short8 b[4]) {
        #pragma unroll
        for (int i = 0; i < 4; ++i) {
            *(short8*)&As[buf][(srow + i * 32) * P_LDP + skcol] = a[i];
            *(short8*)&Bs[buf][(srow + i * 32) * P_LDP + skcol] = b[i];
        }
    };

    {
        short8 a0[4], b0[4];
        loadTile(0, a0, b0);
        writeTile(0, a0, b0);
    }
    __syncthreads();

    int cur = 0;
    for (int it = 0; it < P_NT; ++it) {
        short8 a2[4], b2[4];
        if (it + 1 < P_NT) loadTile(it + 1, a2, b2);

        #pragma unroll
        for (int ks = 0; ks < P_BK; ks += 32) {
            short8 af[4], bf_[4];
            #pragma unroll
            for (int mi = 0; mi < 4; ++mi)
                af[mi] = *(const short8*)&As[cur][(wr * 64 + mi * 16 + lr) * P_LDP + ks + lk];
            #pragma unroll
            for (int ni = 0; ni < 4; ++ni)
                bf_[ni] = *(const short8*)&Bs[cur][(wc * 64 + ni * 16 + lr) * P_LDP + ks + lk];
            #pragma unroll
            for (int mi = 0; mi < 4; ++mi)
                #pragma unroll
                for (int ni = 0; ni < 4; ++ni)
                    acc[mi][ni] = __builtin_amdgcn_mfma_f32_16x16x32_bf16(
                        af[mi], bf_[ni], acc[mi][ni], 0, 0, 0);
        }
        if (it + 1 < P_NT) {
            writeTile(cur ^ 1, a2, b2);
            __syncthreads();
            cur ^= 1;
        }
    }

    #pragma unroll
    for (int mi = 0; mi < 4; ++mi) {
        #pragma unroll
        for (int ni = 0; ni < 4; ++ni) {
            int mloc = m0 + wc * 64 + ni * 16 + lr;
            float bias = convb[mloc];
            #pragma unroll
            for (int j = 0; j < 4; ++j) {
                int g = n0 + wr * 64 + mi * 16 + (lane >> 4) * 4 + j;
                rpre[(size_t)g * M_ + mloc] = f2bf(acc[mi][ni][j] + bias);
            }
        }
    }
}

// ---------------- Phase 3: persistent chain v5 ----------------
// R8 skeleton (144 blocks = 16 rg x 9 cg, 64x128 tile, relaxed padded barrier, agent h
// stores). Change: A(h) fragments load DIRECT to registers via agent atomics with a
// 4-K-tile-deep queue (no A-LDS, no A-barrier); barriers guard only the B LDS dbuf.
#define S_BK 64
#define S_NT (M_ / S_BK)    // 18
#define S_LDP 72
#define N_RG 16
#define N_CG 9

__global__ __launch_bounds__(256) void chain_kernel(
    const unsigned short* __restrict__ w1t,
    const unsigned short* __restrict__ rpre,
    const unsigned short* __restrict__ rbf,
    const float* __restrict__ x,
    unsigned short* h0buf,                  // holds h_0 on entry (parity 0)
    unsigned short* h1buf,                  // parity 1
    float* __restrict__ res,
    unsigned int* bar)                      // 16 counters, 128B apart, zeroed per launch
{
    __shared__ __align__(16) unsigned short Bs[2][128 * S_LDP];   // 36 KiB

    int tid = threadIdx.x;
    int lane = tid & 63;
    int w = tid >> 6;
    int wr = w >> 1, wc = w & 1;            // wave tile: 32 rows x 64 cols
    int bid = blockIdx.x;
    int rg = bid & 15;
    int cg = bid >> 4;
    int n0 = rg * 64;
    int m0 = cg * 128;
    int lr = lane & 15;
    int lg = lane >> 4;
    int srow = tid >> 3;                    // 0..31
    int skcol = (tid & 7) * 8;

    auto ldA8 = [](const unsigned short* p) -> short8 {
        union { u64 q[2]; short8 v; } u;
        u.q[0] = __hip_atomic_load((const u64*)p,       __ATOMIC_RELAXED, __HIP_MEMORY_SCOPE_AGENT);
        u.q[1] = __hip_atomic_load((const u64*)(p + 4), __ATOMIC_RELAXED, __HIP_MEMORY_SCOPE_AGENT);
        return u.v;
    };

    // per-thread A row bases (two fragment rows: mi=0,1)
    int arow0 = n0 + wr * 32 + lr;          // +0, +16

    for (int t = 0; t < NSTEP; ++t) {
        const unsigned short* hin  = (t & 1) ? h1buf : h0buf;
        unsigned short*       hout = (t & 1) ? h0buf : h1buf;
        const unsigned short* rpre_t = rpre + (size_t)t * N_ * M_;
        const unsigned short* rbf_t  = rbf  + (size_t)t * N_ * M_;
        int final_step = (t == NSTEP - 1);

        const unsigned short* hrow0 = hin + (size_t)arow0 * M_ + lg * 8;
        const unsigned short* hrow1 = hrow0 + (size_t)16 * M_;

        // A register queue: slot = it & 3, frags [mi][ks2]
        short8 aQ[4][2][2];
        auto loadAfrag = [&](int it) {
            int slot = it & 3;
            int kb = it * S_BK;
            aQ[slot][0][0] = ldA8(hrow0 + kb);
            aQ[slot][0][1] = ldA8(hrow0 + kb + 32);
            aQ[slot][1][0] = ldA8(hrow1 + kb);
            aQ[slot][1][1] = ldA8(hrow1 + kb + 32);
        };

        // B staging (reg queue depth 2 + LDS dbuf)
        short8 bq0[4], bq1[4];
        auto loadB = [&](int it, short8 b[4]) {
            int kb = it * S_BK;
            #pragma unroll
            for (int i = 0; i < 4; ++i)
                b[i] = *(const short8*)(w1t + (size_t)(m0 + srow + i * 32) * M_ + kb + skcol);
        };
        auto writeB = [&](int buf, short8 b[4]) {
            #pragma unroll
            for (int i = 0; i < 4; ++i)
                *(short8*)&Bs[buf][(srow + i * 32) * S_LDP + skcol] = b[i];
        };

        // prologue: A queue 4 deep, B tile0 staged, tiles 1,2 in regs
        loadAfrag(0); loadAfrag(1); loadAfrag(2); loadAfrag(3);
        loadB(0, bq0);
        writeB(0, bq0);
        loadB(1, bq1);
        loadB(2, bq0);

        // epilogue operand prefetch (cached; latency hides under K-loop)
        unsigned short preR[2][4][4], rbfR[2][4][4];
        #pragma unroll
        for (int mi = 0; mi < 2; ++mi)
            #pragma unroll
            for (int ni = 0; ni < 4; ++ni) {
                int mloc = m0 + wc * 64 + ni * 16 + lr;
                #pragma unroll
                for (int j = 0; j < 4; ++j) {
                    int nloc = n0 + wr * 32 + mi * 16 + lg * 4 + j;
                    preR[mi][ni][j] = rpre_t[(size_t)nloc * M_ + mloc];
                    rbfR[mi][ni][j] = rbf_t[(size_t)nloc * M_ + mloc];
                }
            }
        __syncthreads();

        f32x4 acc[2][4] = {};
        auto compute = [&](int buf, int slot) {
            #pragma unroll
            for (int ks2 = 0; ks2 < 2; ++ks2) {
                short8 bf_[4];
                #pragma unroll
                for (int ni = 0; ni < 4; ++ni)
                    bf_[ni] = *(const short8*)&Bs[buf][(wc * 64 + ni * 16 + lr) * S_LDP + ks2 * 32 + lg * 8];
                #pragma unroll
                for (int mi = 0; mi < 2; ++mi)
                    #pragma unroll
                    for (int ni = 0; ni < 4; ++ni)
                        acc[mi][ni] = __builtin_amdgcn_mfma_f32_16x16x32_bf16(
                            aQ[slot][mi][ks2], bf_[ni], acc[mi][ni], 0, 0, 0);
            }
        };

        int cur = 0;
        #pragma unroll 1
        for (int it2 = 0; it2 < S_NT; it2 += 2) {
            // even iter (tile it2): bq1 holds tile it2+1
            compute(cur, it2 & 3);
            if (it2 + 4 < S_NT) loadAfrag(it2 + 4);
            writeB(cur ^ 1, bq1);
            if (it2 + 3 < S_NT) loadB(it2 + 3, bq1);
            __syncthreads();
            cur ^= 1;
            // odd iter (tile it2+1): bq0 holds tile it2+2
            compute(cur, (it2 + 1) & 3);
            if (it2 + 5 < S_NT) loadAfrag(it2 + 5);
            if (it2 + 2 < S_NT) {
                writeB(cur ^ 1, bq0);
                if (it2 + 4 < S_NT) loadB(it2 + 4, bq0);
                __syncthreads();
                cur ^= 1;
            }
        }

        // epilogue
        #pragma unroll
        for (int mi = 0; mi < 2; ++mi) {
            #pragma unroll
            for (int ni = 0; ni < 4; ++ni) {
                int mloc = m0 + wc * 64 + ni * 16 + lr;
                #pragma unroll
                for (int j = 0; j < 4; ++j) {
                    int nloc = n0 + wr * 32 + mi * 16 + lg * 4 + j;
                    float pre = acc[mi][ni][j] + bf2f(preR[mi][ni][j]);
                    float hv = tanhf(pre) + bf2f(rbfR[mi][ni][j]);
                    if (final_step) {
                        res[(size_t)nloc * M_ + mloc] = tanhf(tanhf(hv) + x[(size_t)nloc * M_ + mloc]);
                    } else {
                        __hip_atomic_store(&hout[(size_t)nloc * M_ + mloc], f2bf(hv),
                                           __ATOMIC_RELAXED, __HIP_MEMORY_SCOPE_AGENT);
                    }
                }
            }
        }

        // per-rowgroup barrier (fan-in 9), relaxed counters 128B apart
        if (!final_step) {
            __syncthreads();   // drains vmcnt(0) per wave -> h stores at coherence point
            if (tid == 0) {
                __hip_atomic_fetch_add(&bar[rg << 5], 1u,
                                       __ATOMIC_RELAXED, __HIP_MEMORY_SCOPE_AGENT);
                unsigned int target = (unsigned)N_CG * (unsigned)(t + 1);
                while (__hip_atomic_load(&bar[rg << 5], __ATOMIC_RELAXED,
                                         __HIP_MEMORY_SCOPE_AGENT) < target) {
                    __builtin_amdgcn_s_sleep(1);
                }
            }
            __syncthreads();
        }
    }
}

// out[n][j] = conv2b + sum_k res[n][j+k] * conv2W[k]
__global__ __launch_bounds__(256) void conv_out_kernel(
    const float* __restrict__ res, const float* __restrict__ w2,
    const float* __restrict__ b2, float* __restrict__ out)
{
    __shared__ float row[M_];
    __shared__ float wk[CONVK];
    int n = blockIdx.x;
    int tid = threadIdx.x;
    for (int i = tid; i < M_; i += 256) row[i] = res[(size_t)n * M_ + i];
    if (tid < CONVK) wk[tid] = w2[tid];
    __syncthreads();
    float b = b2[0];
    int j0 = tid * 4;
    float s0 = b, s1 = b, s2 = b, s3 = b;
    float r0 = row[j0], r1 = row[j0 + 1], r2 = row[j0 + 2], r3 = row[j0 + 3];
    for (int k = 0; k < CONVK; ++k) {
        float wv = wk[k];
        s0 += r0 * wv; s1 += r1 * wv; s2 += r2 * wv; s3 += r3 * wv;
        if (k < CONVK - 1) { r0 = r1; r1 = r2; r2 = r3; r3 = row[j0 + 4 + k]; }
    }
    float* o = out + (size_t)n * OUTW + j0;
    o[0] = s0; o[1] = s1; o[2] = s2; o[3] = s3;
}

extern "C" void kernel_launch(void* const* d_in, const int* in_sizes, int n_in,
                              void* d_out, int out_size, void* d_ws, size_t ws_size,
                              hipStream_t stream) {
    const float* NATree = (const float*)d_in[0];
    const float* x      = (const float*)d_in[1];
    const float* convW  = (const float*)d_in[2];
    const float* convb  = (const float*)d_in[3];
    const float* conv2W = (const float*)d_in[4];
    const float* conv2b = (const float*)d_in[5];
    float* out = (float*)d_out;

    char* ws = (char*)d_ws;
    size_t off = 0;
    auto alloc = [&](size_t bytes) {
        void* p = ws + off;
        off = (off + bytes + 255) & ~(size_t)255;
        return p;
    };
    unsigned short* w0t  = (unsigned short*)alloc((size_t)M_ * M_ * 2);
    unsigned short* w1t  = (unsigned short*)alloc((size_t)M_ * M_ * 2);
    unsigned short* hA   = (unsigned short*)alloc((size_t)N_ * M_ * 2);
    unsigned short* hB   = (unsigned short*)alloc((size_t)N_ * M_ * 2);
    unsigned short* rpre = (unsigned short*)alloc((size_t)NSTEP * N_ * M_ * 2);
    unsigned short* rbf  = (unsigned short*)alloc((size_t)NSTEP * N_ * M_ * 2);
    float*          res  = (float*)alloc((size_t)N_ * M_ * 4);
    unsigned int*   bar  = (unsigned int*)alloc(4096);

    hipMemsetAsync(bar, 0, 4096, stream);
    build_wsplit<<<(M_ * M_ + 255) / 256, 256, 0, stream>>>(convW, w0t, w1t);
    build_h0<<<(N_ * M_ + 255) / 256, 256, 0, stream>>>(NATree, hA);
    build_rbf<<<(NSTEP * N_ * M_ / 8 + 255) / 256, 256, 0, stream>>>(NATree, rbf);

    // Phase 1: all 31 r_t @ W0^T + b in one GEMM (M = 31744)
    rpre_gemm<<<dim3(M_ / P_BN, (NSTEP * N_) / P_BM), 256, 0, stream>>>(rbf, w0t, convb, rpre);

    // Phase 3: persistent chain v5 (144 blocks; A direct-to-reg 4-deep queue)
    chain_kernel<<<N_RG * N_CG, 256, 0, stream>>>(w1t, rpre, rbf, x, hA, hB, res, bar);

    conv_out_kernel<<<1024, 256, 0, stream>>>(res, conv2W, conv2b, out);
}

// Round 12
// 688.238 us; speedup vs baseline: 2.2111x; 2.2111x over previous
//
#include <hip/hip_runtime.h>
#include <hip/hip_bf16.h>

#define N_ 1024
#define M_ 1152
#define L_ 32
#define NATSTRIDE (L_*M_)   // 36864
#define CONVK 129
#define OUTW 1024
#define NSTEP 31

typedef __attribute__((ext_vector_type(8))) short short8;
typedef __attribute__((ext_vector_type(4))) float f32x4;

__device__ __forceinline__ unsigned short f2bf(float f) {
    unsigned int u = __float_as_uint(f);
    u += 0x7FFFu + ((u >> 16) & 1u);   // round-to-nearest-even
    return (unsigned short)(u >> 16);
}
__device__ __forceinline__ float bf2f(unsigned short b) {
    return __uint_as_float(((unsigned int)b) << 16);
}

// Split convW[m][k][2] -> w0t[m][k], w1t[m][k] (bf16, k-contiguous = B^T layout)
__global__ __launch_bounds__(256) void build_wsplit(const float* __restrict__ convW,
                                                    unsigned short* __restrict__ w0t,
                                                    unsigned short* __restrict__ w1t) {
    int idx = blockIdx.x * blockDim.x + threadIdx.x;
    if (idx >= M_ * M_) return;
    int m = idx / M_;
    int k = idx - m * M_;
    const float* s = convW + (size_t)m * (2 * M_) + 2 * k;
    w0t[idx] = f2bf(s[0]);
    w1t[idx] = f2bf(s[1]);
}

// h0 = bf16(NATree[:, L-1, :])
__global__ __launch_bounds__(256) void build_h0(const float* __restrict__ nat,
                                                unsigned short* __restrict__ h0) {
    int idx = blockIdx.x * blockDim.x + threadIdx.x;
    if (idx >= N_ * M_) return;
    int n = idx / M_;
    int m = idx - n * M_;
    h0[idx] = f2bf(nat[(size_t)n * NATSTRIDE + (size_t)(L_ - 1) * M_ + m]);
}

// rbf[t][n][m] = bf16(NATree[n][30-t][m])  for t = 0..30
__global__ __launch_bounds__(256) void build_rbf(const float* __restrict__ nat,
                                                 unsigned short* __restrict__ rbf) {
    int idx = blockIdx.x * blockDim.x + threadIdx.x;   // one thread per 8 elems
    if (idx >= NSTEP * N_ * M_ / 8) return;
    int o = idx * 8;
    int t = o / (N_ * M_);
    int rem = o - t * (N_ * M_);
    int n = rem / M_;
    int m = rem - n * M_;
    int l = (NSTEP - 1) - t;
    const float* s = nat + (size_t)n * NATSTRIDE + (size_t)l * M_ + m;
    f32x4 v0 = *(const f32x4*)(s);
    f32x4 v1 = *(const f32x4*)(s + 4);
    short8 tt;
    #pragma unroll
    for (int e = 0; e < 4; ++e) {
        tt[e]     = (short)f2bf(v0[e]);
        tt[4 + e] = (short)f2bf(v1[e]);
    }
    *(short8*)(rbf + o) = tt;
}

// ---------------- Phase 1: Rpre = bf16( r_t @ W0^T + b ) for all t (unchanged) ----------------
#define P_BM 128
#define P_BN 128
#define P_BK 64
#define P_NT (M_ / P_BK)    // 18
#define P_LDP 72

__global__ __launch_bounds__(256) void rpre_gemm(
    const unsigned short* __restrict__ rbf,
    const unsigned short* __restrict__ w0t,
    const float* __restrict__ convb,
    unsigned short* __restrict__ rpre)
{
    __shared__ __align__(16) unsigned short As[2][P_BM * P_LDP];
    __shared__ __align__(16) unsigned short Bs[2][P_BN * P_LDP];

    int tid = threadIdx.x;
    int lane = tid & 63;
    int w = tid >> 6;
    int wr = w >> 1, wc = w & 1;
    int raw = blockIdx.y * 9 + blockIdx.x;
    int logical = (raw & 7) * 279 + (raw >> 3);   // 2232 = 8*279 bijective chunked swizzle
    int bx = logical % 9, by = logical / 9;
    int n0 = by * P_BM;
    int m0 = bx * P_BN;

    int lr = lane & 15;
    int lk = (lane >> 4) * 8;
    int srow = tid >> 3;
    int skcol = (tid & 7) * 8;

    f32x4 acc[4][4] = {};

    auto loadTile = [&](int it, short8 a[4], short8 b[4]) {
        int kb = it * P_BK;
        #pragma unroll
        for (int i = 0; i < 4; ++i) {
            int row = srow + i * 32;
            a[i] = *(const short8*)(rbf + (size_t)(n0 + row) * M_ + kb + skcol);
            b[i] = *(const short8*)(w0t + (size_t)(m0 + row) * M_ + kb + skcol);
        }
    };
    auto writeTile = [&](int buf, short8 a[4], short8 b[4]) {
        #pragma unroll
        for (int i = 0; i < 4; ++i) {
            *(short8*)&As[buf][(srow + i * 32) * P_LDP + skcol] = a[i];
            *(short8*)&Bs[buf][(srow + i * 32) * P_LDP + skcol] = b[i];
        }
    };

    {
        short8 a0[4], b0[4];
        loadTile(0, a0, b0);
        writeTile(0, a0, b0);
    }
    __syncthreads();

    int cur = 0;
    for (int it = 0; it < P_NT; ++it) {
        short8 a2[4], b2[4];
        if (it + 1 < P_NT) loadTile(it + 1, a2, b2);

        #pragma unroll
        for (int ks = 0; ks < P_BK; ks += 32) {
            short8 af[4], bf_[4];
            #pragma unroll
            for (int mi = 0; mi < 4; ++mi)
                af[mi] = *(const short8*)&As[cur][(wr * 64 + mi * 16 + lr) * P_LDP + ks + lk];
            #pragma unroll
            for (int ni = 0; ni < 4; ++ni)
                bf_[ni] = *(const short8*)&Bs[cur][(wc * 64 + ni * 16 + lr) * P_LDP + ks + lk];
            #pragma unroll
            for (int mi = 0; mi < 4; ++mi)
                #pragma unroll
                for (int ni = 0; ni < 4; ++ni)
                    acc[mi][ni] = __builtin_amdgcn_mfma_f32_16x16x32_bf16(
                        af[mi], bf_[ni], acc[mi][ni], 0, 0, 0);
        }
        if (it + 1 < P_NT) {
            writeTile(cur ^ 1, a2, b2);
            __syncthreads();
            cur ^= 1;
        }
    }

    #pragma unroll
    for (int mi = 0; mi < 4; ++mi) {
        #pragma unroll
        for (int ni = 0; ni < 4; ++ni) {
            int mloc = m0 + wc * 64 + ni * 16 + lr;
            float bias = convb[mloc];
            #pragma unroll
            for (int j = 0; j < 4; ++j) {
                int g = n0 + wr * 64 + mi * 16 + (lane >> 4) * 4 + j;
                rpre[(size_t)g * M_ + mloc] = f2bf(acc[mi][ni][j] + bias);
            }
        }
    }
}

// ---------------- Phase 3 (x31 launches): panel_step ----------------
// 144 blocks = 8 rg (128 rows; bid%8=rg -> h panel XCD-local) x 18 cg (64 cols).
// W1 col-panel (64x1152, 145 KiB) staged into LDS once; ONE barrier; then a
// fully-unrolled 36-iter K-loop with ZERO barriers: B via ds_read_b128 from the
// resident panel, A via plain cached loads in a 4-deep register queue.
// Coherence across steps comes from kernel dispatch boundaries (no atomics/fences).
#define PS_LDP 1160          // 64 B-rows x 1160 elems = 148480 B LDS (16B-aligned rows)

__global__ __launch_bounds__(256) void panel_step(
    const unsigned short* __restrict__ hin,
    const unsigned short* __restrict__ w1t,
    const unsigned short* __restrict__ rpre_t,
    const unsigned short* __restrict__ rbf_t,
    const float* __restrict__ x,
    unsigned short* __restrict__ hout,
    float* __restrict__ resOut,
    int final_step)
{
    __shared__ __align__(16) unsigned short Bs[64 * PS_LDP];

    int tid = threadIdx.x;
    int lane = tid & 63;
    int w = tid >> 6;                 // wave -> rows [32w, 32w+32)
    int bid = blockIdx.x;
    int rg = bid & 7;
    int cg = bid >> 3;
    int n0 = rg * 128;
    int m0 = cg * 64;
    int lr = lane & 15;
    int lg = lane >> 4;

    // ---- stage W1 col-panel into LDS (once per launch)
    {
        int col = tid >> 2;           // 0..63
        int q = tid & 3;
        const unsigned short* src = w1t + (size_t)(m0 + col) * M_;
        unsigned short* dst = &Bs[col * PS_LDP];
        #pragma unroll
        for (int j = 0; j < 36; ++j) {
            int e = (q + 4 * j) * 8;
            *(short8*)(dst + e) = *(const short8*)(src + e);
        }
    }

    // ---- A register queue (plain cached loads), 4 K-slices deep
    const unsigned short* hrow0 = hin + (size_t)(n0 + 32 * w + lr) * M_ + lg * 8;
    const unsigned short* hrow1 = hrow0 + (size_t)16 * M_;
    short8 aQ[4][2];
    auto loadA = [&](int it) {
        int s = it & 3;
        aQ[s][0] = *(const short8*)(hrow0 + it * 32);
        aQ[s][1] = *(const short8*)(hrow1 + it * 32);
    };
    loadA(0); loadA(1); loadA(2); loadA(3);

    // ---- epilogue operand prefetch (latency hides under the K-loop)
    unsigned short preR[2][4][4], rbfR[2][4][4];
    #pragma unroll
    for (int mi = 0; mi < 2; ++mi)
        #pragma unroll
        for (int ni = 0; ni < 4; ++ni) {
            int mloc = m0 + ni * 16 + lr;
            #pragma unroll
            for (int j = 0; j < 4; ++j) {
                int nloc = n0 + 32 * w + 16 * mi + lg * 4 + j;
                preR[mi][ni][j] = rpre_t[(size_t)nloc * M_ + mloc];
                rbfR[mi][ni][j] = rbf_t[(size_t)nloc * M_ + mloc];
            }
        }

    __syncthreads();   // B panel ready; only barrier before epilogue

    // ---- barrier-free K-loop: 36 iters, fully unrolled
    f32x4 acc[2][4] = {};
    #pragma unroll
    for (int it = 0; it < 36; ++it) {
        short8 bf_[4];
        #pragma unroll
        for (int ni = 0; ni < 4; ++ni)
            bf_[ni] = *(const short8*)&Bs[(ni * 16 + lr) * PS_LDP + it * 32 + lg * 8];
        int s = it & 3;   // compile-time (loop unrolled)
        #pragma unroll
        for (int ni = 0; ni < 4; ++ni) {
            acc[0][ni] = __builtin_amdgcn_mfma_f32_16x16x32_bf16(aQ[s][0], bf_[ni], acc[0][ni], 0, 0, 0);
            acc[1][ni] = __builtin_amdgcn_mfma_f32_16x16x32_bf16(aQ[s][1], bf_[ni], acc[1][ni], 0, 0, 0);
        }
        if (it + 4 < 36) loadA(it + 4);
    }

    // ---- epilogue (plain stores; dispatch boundary provides coherence)
    #pragma unroll
    for (int mi = 0; mi < 2; ++mi) {
        #pragma unroll
        for (int ni = 0; ni < 4; ++ni) {
            int mloc = m0 + ni * 16 + lr;
            #pragma unroll
            for (int j = 0; j < 4; ++j) {
                int nloc = n0 + 32 * w + 16 * mi + lg * 4 + j;
                float pre = acc[mi][ni][j] + bf2f(preR[mi][ni][j]);
                float hv = tanhf(pre) + bf2f(rbfR[mi][ni][j]);
                if (final_step) {
                    resOut[(size_t)nloc * M_ + mloc] = tanhf(tanhf(hv) + x[(size_t)nloc * M_ + mloc]);
                } else {
                    hout[(size_t)nloc * M_ + mloc] = f2bf(hv);
                }
            }
        }
    }
}

// out[n][j] = conv2b + sum_k res[n][j+k] * conv2W[k]
__global__ __launch_bounds__(256) void conv_out_kernel(
    const float* __restrict__ res, const float* __restrict__ w2,
    const float* __restrict__ b2, float* __restrict__ out)
{
    __shared__ float row[M_];
    __shared__ float wk[CONVK];
    int n = blockIdx.x;
    int tid = threadIdx.x;
    for (int i = tid; i < M_; i += 256) row[i] = res[(size_t)n * M_ + i];
    if (tid < CONVK) wk[tid] = w2[tid];
    __syncthreads();
    float b = b2[0];
    int j0 = tid * 4;
    float s0 = b, s1 = b, s2 = b, s3 = b;
    float r0 = row[j0], r1 = row[j0 + 1], r2 = row[j0 + 2], r3 = row[j0 + 3];
    for (int k = 0; k < CONVK; ++k) {
        float wv = wk[k];
        s0 += r0 * wv; s1 += r1 * wv; s2 += r2 * wv; s3 += r3 * wv;
        if (k < CONVK - 1) { r0 = r1; r1 = r2; r2 = r3; r3 = row[j0 + 4 + k]; }
    }
    float* o = out + (size_t)n * OUTW + j0;
    o[0] = s0; o[1] = s1; o[2] = s2; o[3] = s3;
}

extern "C" void kernel_launch(void* const* d_in, const int* in_sizes, int n_in,
                              void* d_out, int out_size, void* d_ws, size_t ws_size,
                              hipStream_t stream) {
    const float* NATree = (const float*)d_in[0];
    const float* x      = (const float*)d_in[1];
    const float* convW  = (const float*)d_in[2];
    const float* convb  = (const float*)d_in[3];
    const float* conv2W = (const float*)d_in[4];
    const float* conv2b = (const float*)d_in[5];
    float* out = (float*)d_out;

    char* ws = (char*)d_ws;
    size_t off = 0;
    auto alloc = [&](size_t bytes) {
        void* p = ws + off;
        off = (off + bytes + 255) & ~(size_t)255;
        return p;
    };
    unsigned short* w0t  = (unsigned short*)alloc((size_t)M_ * M_ * 2);
    unsigned short* w1t  = (unsigned short*)alloc((size_t)M_ * M_ * 2);
    unsigned short* hA   = (unsigned short*)alloc((size_t)N_ * M_ * 2);
    unsigned short* hB   = (unsigned short*)alloc((size_t)N_ * M_ * 2);
    unsigned short* rpre = (unsigned short*)alloc((size_t)NSTEP * N_ * M_ * 2);
    unsigned short* rbf  = (unsigned short*)alloc((size_t)NSTEP * N_ * M_ * 2);
    float*          res  = (float*)alloc((size_t)N_ * M_ * 4);

    build_wsplit<<<(M_ * M_ + 255) / 256, 256, 0, stream>>>(convW, w0t, w1t);
    build_h0<<<(N_ * M_ + 255) / 256, 256, 0, stream>>>(NATree, hA);
    build_rbf<<<(NSTEP * N_ * M_ / 8 + 255) / 256, 256, 0, stream>>>(NATree, rbf);

    // Phase 1: all 31 r_t @ W0^T + b in one GEMM (M = 31744)
    rpre_gemm<<<dim3(M_ / P_BN, (NSTEP * N_) / P_BM), 256, 0, stream>>>(rbf, w0t, convb, rpre);

    // Phase 3: sequential h-chain, barrier-free K-loop per step
    const unsigned short* hin = hA;
    unsigned short* hout = hB;
    for (int t = 0; t < NSTEP; ++t) {
        int fin = (t == NSTEP - 1) ? 1 : 0;
        panel_step<<<144, 256, 0, stream>>>(
            hin, w1t, rpre + (size_t)t * N_ * M_, rbf + (size_t)t * N_ * M_,
            x, hout, res, fin);
        unsigned short* tmp = hout;
        hout = (unsigned short*)hin;
        hin = tmp;
    }

    conv_out_kernel<<<1024, 256, 0, stream>>>(res, conv2W, conv2b, out);
}